// Round 1
// baseline (153.416 us; speedup 1.0000x reference)
//
#include <hip/hip_runtime.h>
#include <hip/hip_bf16.h>
#include <stdint.h>

typedef __attribute__((ext_vector_type(8))) short  s16x8;
typedef __attribute__((ext_vector_type(8))) __bf16 bf16x8;
typedef __attribute__((ext_vector_type(4))) float  f32x4;

#define N_ROWS  32768   // 64 * 512
#define N_CODES 1024
#define DIM     512

static __device__ __forceinline__ short f2bf(float f) {
    unsigned u = __float_as_uint(f);
    u += 0x7fffu + ((u >> 16) & 1u);   // round-to-nearest-even
    return (short)(u >> 16);
}

// ---------------- K1: codebook norms ----------------
__global__ void __launch_bounds__(256)
wnorm_kernel(const float* __restrict__ W, float* __restrict__ wnorm) {
    const int lane = threadIdx.x & 63;
    const int code = blockIdx.x * 4 + (threadIdx.x >> 6);
    const float4* wp = (const float4*)(W + (size_t)code * DIM + lane * 8);
    float4 a = wp[0], b = wp[1];
    float s = a.x*a.x + a.y*a.y + a.z*a.z + a.w*a.w
            + b.x*b.x + b.y*b.y + b.z*b.z + b.w*b.w;
    #pragma unroll
    for (int d = 1; d < 64; d <<= 1) s += __shfl_xor(s, d);
    if (lane == 0) wnorm[code] = s;
}

// ---------------- K2: bf16 MFMA GEMM + per-tile argmin ----------------
// 128x128 tile, BK=32, 4 waves (2x2), each wave 64x64 (4x4 frags of 16x16x32).
#define LDSP 40   // padded LDS row stride in shorts (80 B) — spreads banks
__global__ void __launch_bounds__(256)
gemm_argmin(const float* __restrict__ X, const float* __restrict__ W,
            const float* __restrict__ wnorm, float2* __restrict__ pairs) {
    __shared__ __align__(16) short As[128 * LDSP];
    __shared__ __align__(16) short Bs[128 * LDSP];

    const int tid  = threadIdx.x;
    const int lane = tid & 63;
    const int wave = tid >> 6;
    const int wr = wave >> 1, wc = wave & 1;
    const int lr = lane & 15, lk = (lane >> 4) * 8;

    const int colBase = blockIdx.x * 128;   // code dim (8 blocks)
    const int rowBase = blockIdx.y * 128;   // row dim (256 blocks)

    f32x4 acc[4][4];
    #pragma unroll
    for (int m = 0; m < 4; ++m)
        #pragma unroll
        for (int n = 0; n < 4; ++n) acc[m][n] = (f32x4)0.f;

    const int sr = tid >> 1;            // staging row 0..127
    const int sh = (tid & 1) * 16;      // staging col offset (floats)
    const float* xsrc = X + (size_t)(rowBase + sr) * DIM + sh;
    const float* wsrc = W + (size_t)(colBase + sr) * DIM + sh;
    short* adst = &As[sr * LDSP + sh];
    short* bdst = &Bs[sr * LDSP + sh];

    for (int kt = 0; kt < DIM; kt += 32) {
        float4 x0 = *(const float4*)(xsrc + kt);
        float4 x1 = *(const float4*)(xsrc + kt + 4);
        float4 x2 = *(const float4*)(xsrc + kt + 8);
        float4 x3 = *(const float4*)(xsrc + kt + 12);
        float4 w0 = *(const float4*)(wsrc + kt);
        float4 w1 = *(const float4*)(wsrc + kt + 4);
        float4 w2 = *(const float4*)(wsrc + kt + 8);
        float4 w3 = *(const float4*)(wsrc + kt + 12);
        s16x8 av0 = { f2bf(x0.x), f2bf(x0.y), f2bf(x0.z), f2bf(x0.w),
                      f2bf(x1.x), f2bf(x1.y), f2bf(x1.z), f2bf(x1.w) };
        s16x8 av1 = { f2bf(x2.x), f2bf(x2.y), f2bf(x2.z), f2bf(x2.w),
                      f2bf(x3.x), f2bf(x3.y), f2bf(x3.z), f2bf(x3.w) };
        s16x8 bv0 = { f2bf(w0.x), f2bf(w0.y), f2bf(w0.z), f2bf(w0.w),
                      f2bf(w1.x), f2bf(w1.y), f2bf(w1.z), f2bf(w1.w) };
        s16x8 bv1 = { f2bf(w2.x), f2bf(w2.y), f2bf(w2.z), f2bf(w2.w),
                      f2bf(w3.x), f2bf(w3.y), f2bf(w3.z), f2bf(w3.w) };
        *(s16x8*)(adst)     = av0;
        *(s16x8*)(adst + 8) = av1;
        *(s16x8*)(bdst)     = bv0;
        *(s16x8*)(bdst + 8) = bv1;
        __syncthreads();

        bf16x8 aF[4], bF[4];
        #pragma unroll
        for (int m = 0; m < 4; ++m)
            aF[m] = __builtin_bit_cast(bf16x8,
                *(const s16x8*)&As[(wr*64 + m*16 + lr) * LDSP + lk]);
        #pragma unroll
        for (int n = 0; n < 4; ++n)
            bF[n] = __builtin_bit_cast(bf16x8,
                *(const s16x8*)&Bs[(wc*64 + n*16 + lr) * LDSP + lk]);
        #pragma unroll
        for (int m = 0; m < 4; ++m)
            #pragma unroll
            for (int n = 0; n < 4; ++n)
                acc[m][n] = __builtin_amdgcn_mfma_f32_16x16x32_bf16(
                    aF[m], bF[n], acc[m][n], 0, 0, 0);
        __syncthreads();
    }

    // Epilogue: score = wnorm[col] - 2*dot; per-row argmin over this wave's
    // 64 columns, then write (min, idx) for chunk = colBlk*2 + wc.
    float wn[4]; int wcol[4];
    #pragma unroll
    for (int n = 0; n < 4; ++n) {
        wcol[n] = colBase + wc*64 + n*16 + lr;
        wn[n] = wnorm[wcol[n]];
    }
    #pragma unroll
    for (int m = 0; m < 4; ++m) {
        #pragma unroll
        for (int r = 0; r < 4; ++r) {
            float bv = wn[0] - 2.0f * acc[m][0][r];
            int   bi = wcol[0];
            #pragma unroll
            for (int n = 1; n < 4; ++n) {
                float sc = wn[n] - 2.0f * acc[m][n][r];
                if (sc < bv) { bv = sc; bi = wcol[n]; }
            }
            #pragma unroll
            for (int d = 1; d < 16; d <<= 1) {
                float ov = __shfl_xor(bv, d);
                int   oi = __shfl_xor(bi, d);
                if (ov < bv || (ov == bv && oi < bi)) { bv = ov; bi = oi; }
            }
            if (lr == 0) {
                int row = rowBase + wr*64 + m*16 + (lane >> 4) * 4 + r;
                pairs[(size_t)row * 16 + blockIdx.x * 2 + wc] =
                    make_float2(bv, __int_as_float(bi));
            }
        }
    }
}

// ---------------- K3: combine 16 chunk-minima, exact f32 row loss ----------------
__global__ void __launch_bounds__(256)
combine_loss(const float* __restrict__ X, const float* __restrict__ W,
             const float2* __restrict__ pairs, float* __restrict__ rowloss) {
    const int lane = threadIdx.x & 63;
    const int row  = blockIdx.x * 4 + (threadIdx.x >> 6);
    float bv; int bi;
    if (lane < 16) {
        float2 p = pairs[(size_t)row * 16 + lane];
        bv = p.x; bi = __float_as_int(p.y);
    } else {
        bv = __int_as_float(0x7f800000);  // +inf
        bi = 0x7fffffff;
    }
    #pragma unroll
    for (int d = 1; d < 64; d <<= 1) {
        float ov = __shfl_xor(bv, d);
        int   oi = __shfl_xor(bi, d);
        if (ov < bv || (ov == bv && oi < bi)) { bv = ov; bi = oi; }
    }
    const float4* xp = (const float4*)(X + (size_t)row * DIM + lane * 8);
    const float4* wp = (const float4*)(W + (size_t)bi  * DIM + lane * 8);
    float4 x0 = xp[0], x1 = xp[1];
    float4 w0 = wp[0], w1 = wp[1];
    float s = 0.f, d0;
    d0 = x0.x - w0.x; s += d0*d0;  d0 = x0.y - w0.y; s += d0*d0;
    d0 = x0.z - w0.z; s += d0*d0;  d0 = x0.w - w0.w; s += d0*d0;
    d0 = x1.x - w1.x; s += d0*d0;  d0 = x1.y - w1.y; s += d0*d0;
    d0 = x1.z - w1.z; s += d0*d0;  d0 = x1.w - w1.w; s += d0*d0;
    #pragma unroll
    for (int d = 1; d < 64; d <<= 1) s += __shfl_xor(s, d);
    if (lane == 0) rowloss[row] = s;
}

// ---------------- K4: deterministic final mean (double accum) ----------------
__global__ void __launch_bounds__(256)
finalize(const float* __restrict__ rowloss, float* __restrict__ out) {
    __shared__ double sm[256];
    double s = 0.0;
    for (int i = threadIdx.x; i < N_ROWS; i += 256) s += (double)rowloss[i];
    sm[threadIdx.x] = s;
    __syncthreads();
    for (int st = 128; st > 0; st >>= 1) {
        if (threadIdx.x < st) sm[threadIdx.x] += sm[threadIdx.x + st];
        __syncthreads();
    }
    if (threadIdx.x == 0)
        out[0] = (float)(sm[0] / (double)((size_t)N_ROWS * DIM));
}

extern "C" void kernel_launch(void* const* d_in, const int* in_sizes, int n_in,
                              void* d_out, int out_size, void* d_ws, size_t ws_size,
                              hipStream_t stream) {
    const float* X = (const float*)d_in[0];   // [32768][512]
    const float* W = (const float*)d_in[1];   // [1024][512]
    char* ws = (char*)d_ws;
    float*  wnorm   = (float*)ws;                                   // 4 KB
    float2* pairs   = (float2*)(ws + 4096);                         // 4 MB
    float*  rowloss = (float*)(ws + 4096 + (size_t)N_ROWS * 16 * 8);// 128 KB
    float*  out     = (float*)d_out;

    wnorm_kernel<<<N_CODES / 4, 256, 0, stream>>>(W, wnorm);
    gemm_argmin<<<dim3(8, 256), 256, 0, stream>>>(X, W, wnorm, pairs);
    combine_loss<<<N_ROWS / 4, 256, 0, stream>>>(X, W, pairs, rowloss);
    finalize<<<1, 256, 0, stream>>>(rowloss, out);
}

// Round 2
// 141.266 us; speedup vs baseline: 1.0860x; 1.0860x over previous
//
#include <hip/hip_runtime.h>
#include <hip/hip_bf16.h>
#include <stdint.h>

typedef __attribute__((ext_vector_type(8))) short  s16x8;
typedef __attribute__((ext_vector_type(8))) __bf16 bf16x8;
typedef __attribute__((ext_vector_type(4))) float  f32x4;

#define N_ROWS  32768   // 64 * 512
#define N_CODES 1024
#define DIM     512
#define BK      64      // K-tile (bf16 elements)

static __device__ __forceinline__ short f2bf(float f) {
    unsigned u = __float_as_uint(f);
    u += 0x7fffu + ((u >> 16) & 1u);   // round-to-nearest-even
    return (short)(u >> 16);
}

typedef const __attribute__((address_space(1))) uint32_t guint;
typedef __attribute__((address_space(3))) uint32_t luint;
static __device__ __forceinline__ void gl_lds16(const short* g, short* l) {
    __builtin_amdgcn_global_load_lds((guint*)g, (luint*)l, 16, 0, 0);
}

// ---------------- K0a: convert X to bf16 (row-major, same layout) ----------------
__global__ void __launch_bounds__(256)
convertX(const float* __restrict__ X, short* __restrict__ Xb) {
    const size_t i = ((size_t)blockIdx.x * 256 + threadIdx.x) * 8;
    float4 a = *(const float4*)(X + i);
    float4 b = *(const float4*)(X + i + 4);
    s16x8 v = { f2bf(a.x), f2bf(a.y), f2bf(a.z), f2bf(a.w),
                f2bf(b.x), f2bf(b.y), f2bf(b.z), f2bf(b.w) };
    *(s16x8*)(Xb + i) = v;
}

// ---------------- K0b: convert W to bf16 + codebook norms (f32) ----------------
__global__ void __launch_bounds__(256)
convertW(const float* __restrict__ W, short* __restrict__ Wb,
         float* __restrict__ wnorm) {
    const int lane = threadIdx.x & 63;
    const int code = blockIdx.x * 4 + (threadIdx.x >> 6);
    const float4* wp = (const float4*)(W + (size_t)code * DIM + lane * 8);
    float4 a = wp[0], b = wp[1];
    s16x8 v = { f2bf(a.x), f2bf(a.y), f2bf(a.z), f2bf(a.w),
                f2bf(b.x), f2bf(b.y), f2bf(b.z), f2bf(b.w) };
    *(s16x8*)(Wb + (size_t)code * DIM + lane * 8) = v;
    float s = a.x*a.x + a.y*a.y + a.z*a.z + a.w*a.w
            + b.x*b.x + b.y*b.y + b.z*b.z + b.w*b.w;
    #pragma unroll
    for (int d = 1; d < 64; d <<= 1) s += __shfl_xor(s, d);
    if (lane == 0) wnorm[code] = s;
}

// ---------------- K2: bf16 MFMA GEMM + per-tile argmin ----------------
// 128x128 tile, BK=64, 4 waves (2x2), wave = 64x64 (4x4 frags of 16x16x32).
// global_load_lds (16B) into linear LDS; XOR swizzle applied on the global
// SOURCE address (stage) and the ds_read address (consume) — rule both-sides.
__global__ void __launch_bounds__(256)
gemm_argmin(const short* __restrict__ Xb, const short* __restrict__ Wb,
            const float* __restrict__ wnorm, float2* __restrict__ pairs) {
    __shared__ __align__(16) short As[2][128 * BK];
    __shared__ __align__(16) short Bs[2][128 * BK];

    const int tid  = threadIdx.x;
    const int lane = tid & 63;
    const int wave = tid >> 6;
    const int wr = wave >> 1, wc = wave & 1;
    const int lr = lane & 15, kg = lane >> 4;

    const int colBase = blockIdx.x * 128;   // code dim (8 blocks)
    const int rowBase = blockIdx.y * 128;   // row dim (256 blocks)

    // staging: wave handles chunks wave*4+i (i=0..3); chunk = 8 rows x 64 k.
    // lane l -> row (l>>3) of chunk, 16B k-slot (l&7), source k XOR-swizzled.
    const int l3 = lane >> 3, l7 = lane & 7;
    const int sk = 8 * (l7 ^ l3);           // swizzled source k-offset (elems)
    const short* gA[4]; const short* gB[4];
    #pragma unroll
    for (int i = 0; i < 4; ++i) {
        const int r = wave * 32 + i * 8 + l3;
        gA[i] = Xb + (size_t)(rowBase + r) * DIM + sk;
        gB[i] = Wb + (size_t)(colBase + r) * DIM + sk;
    }

    f32x4 acc[4][4];
    #pragma unroll
    for (int m = 0; m < 4; ++m)
        #pragma unroll
        for (int n = 0; n < 4; ++n) acc[m][n] = (f32x4)0.f;

#define STAGE(buf, t) do {                                                   \
    _Pragma("unroll")                                                        \
    for (int i = 0; i < 4; ++i) {                                            \
        const int ch = wave * 4 + i;                                         \
        gl_lds16(gA[i] + (t) * BK, &As[buf][ch * 512 + lane * 8]);           \
        gl_lds16(gB[i] + (t) * BK, &Bs[buf][ch * 512 + lane * 8]);           \
    } } while (0)

    STAGE(0, 0);
    __syncthreads();

    for (int t = 0; t < DIM / BK; ++t) {
        const int cur = t & 1;
        if (t < DIM / BK - 1) STAGE(cur ^ 1, t + 1);
        #pragma unroll
        for (int ks = 0; ks < 2; ++ks) {
            const int q = (ks * 32 + kg * 8) ^ ((lr & 7) * 8);  // swizzled read
            bf16x8 aF[4], bF[4];
            #pragma unroll
            for (int m = 0; m < 4; ++m)
                aF[m] = __builtin_bit_cast(bf16x8,
                    *(const s16x8*)&As[cur][(wr*64 + m*16 + lr) * BK + q]);
            #pragma unroll
            for (int n = 0; n < 4; ++n)
                bF[n] = __builtin_bit_cast(bf16x8,
                    *(const s16x8*)&Bs[cur][(wc*64 + n*16 + lr) * BK + q]);
            #pragma unroll
            for (int m = 0; m < 4; ++m)
                #pragma unroll
                for (int n = 0; n < 4; ++n)
                    acc[m][n] = __builtin_amdgcn_mfma_f32_16x16x32_bf16(
                        aF[m], bF[n], acc[m][n], 0, 0, 0);
        }
        __syncthreads();
    }
#undef STAGE

    // Epilogue: score = wnorm[col] - 2*dot; per-row argmin over wave's 64 cols.
    float wn[4]; int wcol[4];
    #pragma unroll
    for (int n = 0; n < 4; ++n) {
        wcol[n] = colBase + wc*64 + n*16 + lr;
        wn[n] = wnorm[wcol[n]];
    }
    #pragma unroll
    for (int m = 0; m < 4; ++m) {
        #pragma unroll
        for (int r = 0; r < 4; ++r) {
            float bv = wn[0] - 2.0f * acc[m][0][r];
            int   bi = wcol[0];
            #pragma unroll
            for (int n = 1; n < 4; ++n) {
                float sc = wn[n] - 2.0f * acc[m][n][r];
                if (sc < bv) { bv = sc; bi = wcol[n]; }
            }
            #pragma unroll
            for (int d = 1; d < 16; d <<= 1) {
                float ov = __shfl_xor(bv, d);
                int   oi = __shfl_xor(bi, d);
                if (ov < bv || (ov == bv && oi < bi)) { bv = ov; bi = oi; }
            }
            if (lr == 0) {
                const int row = rowBase + wr*64 + m*16 + kg*4 + r;
                pairs[(size_t)row * 16 + blockIdx.x * 2 + wc] =
                    make_float2(bv, __int_as_float(bi));
            }
        }
    }
}

// ---------------- K3: combine 16 chunk-minima, exact f32 row loss ----------------
__global__ void __launch_bounds__(256)
combine_loss(const float* __restrict__ X, const float* __restrict__ W,
             const float2* __restrict__ pairs, float* __restrict__ rowloss) {
    const int lane = threadIdx.x & 63;
    const int row  = blockIdx.x * 4 + (threadIdx.x >> 6);
    float bv; int bi;
    if (lane < 16) {
        float2 p = pairs[(size_t)row * 16 + lane];
        bv = p.x; bi = __float_as_int(p.y);
    } else {
        bv = __int_as_float(0x7f800000);  // +inf
        bi = 0x7fffffff;
    }
    #pragma unroll
    for (int d = 1; d < 64; d <<= 1) {
        float ov = __shfl_xor(bv, d);
        int   oi = __shfl_xor(bi, d);
        if (ov < bv || (ov == bv && oi < bi)) { bv = ov; bi = oi; }
    }
    const float4* xp = (const float4*)(X + (size_t)row * DIM + lane * 8);
    const float4* wp = (const float4*)(W + (size_t)bi  * DIM + lane * 8);
    float4 x0 = xp[0], x1 = xp[1];
    float4 w0 = wp[0], w1 = wp[1];
    float s = 0.f, d0;
    d0 = x0.x - w0.x; s += d0*d0;  d0 = x0.y - w0.y; s += d0*d0;
    d0 = x0.z - w0.z; s += d0*d0;  d0 = x0.w - w0.w; s += d0*d0;
    d0 = x1.x - w1.x; s += d0*d0;  d0 = x1.y - w1.y; s += d0*d0;
    d0 = x1.z - w1.z; s += d0*d0;  d0 = x1.w - w1.w; s += d0*d0;
    #pragma unroll
    for (int d = 1; d < 64; d <<= 1) s += __shfl_xor(s, d);
    if (lane == 0) rowloss[row] = s;
}

// ---------------- K4: deterministic final mean (double accum) ----------------
__global__ void __launch_bounds__(256)
finalize(const float* __restrict__ rowloss, float* __restrict__ out) {
    __shared__ double sm[256];
    double s = 0.0;
    for (int i = threadIdx.x; i < N_ROWS; i += 256) s += (double)rowloss[i];
    sm[threadIdx.x] = s;
    __syncthreads();
    for (int st = 128; st > 0; st >>= 1) {
        if (threadIdx.x < st) sm[threadIdx.x] += sm[threadIdx.x + st];
        __syncthreads();
    }
    if (threadIdx.x == 0)
        out[0] = (float)(sm[0] / (double)((size_t)N_ROWS * DIM));
}

extern "C" void kernel_launch(void* const* d_in, const int* in_sizes, int n_in,
                              void* d_out, int out_size, void* d_ws, size_t ws_size,
                              hipStream_t stream) {
    const float* X = (const float*)d_in[0];   // [32768][512]
    const float* W = (const float*)d_in[1];   // [1024][512]
    char* ws = (char*)d_ws;
    float*  wnorm   = (float*)ws;                         // 4 KB
    float2* pairs   = (float2*)(ws + 4096);               // 4 MB
    float*  rowloss = (float*)(ws + 4096 + 4194304);      // 128 KB
    short*  Xb      = (short*)(ws + 8388608);             // 32 MB
    short*  Wb      = (short*)(ws + 8388608 + 33554432);  // 1 MB
    float*  out     = (float*)d_out;

    convertX<<<N_ROWS * DIM / (256 * 8), 256, 0, stream>>>(X, Xb);
    convertW<<<N_CODES / 4, 256, 0, stream>>>(W, Wb, wnorm);
    gemm_argmin<<<dim3(8, 256), 256, 0, stream>>>(Xb, Wb, wnorm, pairs);
    combine_loss<<<N_ROWS / 4, 256, 0, stream>>>(X, W, pairs, rowloss);
    finalize<<<1, 256, 0, stream>>>(rowloss, out);
}

// Round 3
// 106.006 us; speedup vs baseline: 1.4472x; 1.3326x over previous
//
#include <hip/hip_runtime.h>
#include <hip/hip_bf16.h>
#include <stdint.h>

typedef __attribute__((ext_vector_type(8))) short  s16x8;
typedef __attribute__((ext_vector_type(8))) __bf16 bf16x8;
typedef __attribute__((ext_vector_type(4))) float  f32x4;

#define N_ROWS  32768   // 64 * 512
#define N_CODES 1024
#define DIM     512
#define BK      32      // K-tile: wave frag-read spans a contiguous 1KB LDS
                        // region -> conflict-free with LINEAR layout (no swizzle)

static __device__ __forceinline__ short f2bf(float f) {
    unsigned u = __float_as_uint(f);
    u += 0x7fffu + ((u >> 16) & 1u);   // round-to-nearest-even
    return (short)(u >> 16);
}

typedef const __attribute__((address_space(1))) uint32_t guint;
typedef __attribute__((address_space(3))) uint32_t luint;
static __device__ __forceinline__ void gl_lds16(const short* g, short* l) {
    __builtin_amdgcn_global_load_lds((guint*)g, (luint*)l, 16, 0, 0);
}

// ---------------- K0a: convert X to bf16 ----------------
__global__ void __launch_bounds__(256)
convertX(const float* __restrict__ X, short* __restrict__ Xb) {
    const size_t i = ((size_t)blockIdx.x * 256 + threadIdx.x) * 8;
    float4 a = *(const float4*)(X + i);
    float4 b = *(const float4*)(X + i + 4);
    s16x8 v = { f2bf(a.x), f2bf(a.y), f2bf(a.z), f2bf(a.w),
                f2bf(b.x), f2bf(b.y), f2bf(b.z), f2bf(b.w) };
    *(s16x8*)(Xb + i) = v;
}

// ---------------- K0b: convert W to bf16 + codebook norms ----------------
__global__ void __launch_bounds__(256)
convertW(const float* __restrict__ W, short* __restrict__ Wb,
         float* __restrict__ wnorm) {
    const int lane = threadIdx.x & 63;
    const int code = blockIdx.x * 4 + (threadIdx.x >> 6);
    const float4* wp = (const float4*)(W + (size_t)code * DIM + lane * 8);
    float4 a = wp[0], b = wp[1];
    s16x8 v = { f2bf(a.x), f2bf(a.y), f2bf(a.z), f2bf(a.w),
                f2bf(b.x), f2bf(b.y), f2bf(b.z), f2bf(b.w) };
    *(s16x8*)(Wb + (size_t)code * DIM + lane * 8) = v;
    float s = a.x*a.x + a.y*a.y + a.z*a.z + a.w*a.w
            + b.x*b.x + b.y*b.y + b.z*b.z + b.w*b.w;
    #pragma unroll
    for (int d = 1; d < 64; d <<= 1) s += __shfl_xor(s, d);
    if (lane == 0) wnorm[code] = s;
}

// ---------------- K2: bf16 MFMA GEMM + per-tile argmin (m97 structure) ----------------
// 128x128 tile, BK=32, single 16KB LDS buffer, 4 waves (2x2), wave = 64x64.
// 1D grid of 2048, XCD-chunked swizzle: XCD j owns col-block j (Wb slice L2-resident).
__global__ void __launch_bounds__(256)
gemm_argmin(const short* __restrict__ Xb, const short* __restrict__ Wb,
            const float* __restrict__ wnorm, float2* __restrict__ pairs) {
    __shared__ __align__(16) short As[128 * BK];
    __shared__ __align__(16) short Bs[128 * BK];

    const int tid  = threadIdx.x;
    const int lane = tid & 63;
    const int wave = tid >> 6;
    const int wr = wave >> 1, wc = wave & 1;
    const int lr = lane & 15, kg = lane >> 4;

    // XCD-chunked bijective swizzle (nwg=2048, 2048%8==0)
    const int sid = (blockIdx.x & 7) * 256 + (blockIdx.x >> 3);
    const int colBase = (sid >> 8) * 128;   // code dim (8 col-blocks)
    const int rowBase = (sid & 255) * 128;  // row dim (256 row-blocks)

    // staging: wave w stages rows [w*32, w*32+32) of both tiles.
    // lane l -> row w*32 + c*16 + (l>>2), 16B k-slot (l&3). Linear LDS dest.
    const short* aSrc = Xb + (size_t)(rowBase + wave*32 + (lane >> 2)) * DIM + (lane & 3) * 8;
    const short* bSrc = Wb + (size_t)(colBase + wave*32 + (lane >> 2)) * DIM + (lane & 3) * 8;
    short* aDst = &As[wave * 1024 + lane * 8];
    short* bDst = &Bs[wave * 1024 + lane * 8];

    f32x4 acc[4][4];
    #pragma unroll
    for (int m = 0; m < 4; ++m)
        #pragma unroll
        for (int n = 0; n < 4; ++n) acc[m][n] = (f32x4)0.f;

    for (int t = 0; t < DIM / BK; ++t) {
        gl_lds16(aSrc + t * BK,            aDst);
        gl_lds16(aSrc + 16 * DIM + t * BK, aDst + 512);
        gl_lds16(bSrc + t * BK,            bDst);
        gl_lds16(bSrc + 16 * DIM + t * BK, bDst + 512);
        __syncthreads();

        bf16x8 aF[4], bF[4];
        #pragma unroll
        for (int m = 0; m < 4; ++m)
            aF[m] = __builtin_bit_cast(bf16x8,
                *(const s16x8*)&As[(wr*64 + m*16 + lr) * BK + kg * 8]);
        #pragma unroll
        for (int n = 0; n < 4; ++n)
            bF[n] = __builtin_bit_cast(bf16x8,
                *(const s16x8*)&Bs[(wc*64 + n*16 + lr) * BK + kg * 8]);
        #pragma unroll
        for (int m = 0; m < 4; ++m)
            #pragma unroll
            for (int n = 0; n < 4; ++n)
                acc[m][n] = __builtin_amdgcn_mfma_f32_16x16x32_bf16(
                    aF[m], bF[n], acc[m][n], 0, 0, 0);
        __syncthreads();
    }

    // Epilogue: score = wnorm[col] - 2*dot; per-row argmin over wave's 64 cols.
    float wn[4]; int wcol[4];
    #pragma unroll
    for (int n = 0; n < 4; ++n) {
        wcol[n] = colBase + wc*64 + n*16 + lr;
        wn[n] = wnorm[wcol[n]];
    }
    #pragma unroll
    for (int m = 0; m < 4; ++m) {
        #pragma unroll
        for (int r = 0; r < 4; ++r) {
            float bv = wn[0] - 2.0f * acc[m][0][r];
            int   bi = wcol[0];
            #pragma unroll
            for (int n = 1; n < 4; ++n) {
                float sc = wn[n] - 2.0f * acc[m][n][r];
                if (sc < bv) { bv = sc; bi = wcol[n]; }
            }
            #pragma unroll
            for (int d = 1; d < 16; d <<= 1) {
                float ov = __shfl_xor(bv, d);
                int   oi = __shfl_xor(bi, d);
                if (ov < bv || (ov == bv && oi < bi)) { bv = ov; bi = oi; }
            }
            if (lr == 0) {
                const int row = rowBase + wr*64 + m*16 + kg*4 + r;
                pairs[(size_t)row * 16 + (colBase >> 6) + wc] =
                    make_float2(bv, __int_as_float(bi));
            }
        }
    }
}

// ---------------- K3: combine 16 chunk-minima, exact f32 row loss, block partial ----------------
__global__ void __launch_bounds__(256)
combine_loss(const float* __restrict__ X, const float* __restrict__ W,
             const float2* __restrict__ pairs, float* __restrict__ partial) {
    __shared__ float psum[4];
    const int lane = threadIdx.x & 63;
    const int wv   = threadIdx.x >> 6;
    const int row  = blockIdx.x * 4 + wv;
    float bv; int bi;
    if (lane < 16) {
        float2 p = pairs[(size_t)row * 16 + lane];
        bv = p.x; bi = __float_as_int(p.y);
    } else {
        bv = __int_as_float(0x7f800000);  // +inf
        bi = 0x7fffffff;
    }
    #pragma unroll
    for (int d = 1; d < 64; d <<= 1) {
        float ov = __shfl_xor(bv, d);
        int   oi = __shfl_xor(bi, d);
        if (ov < bv || (ov == bv && oi < bi)) { bv = ov; bi = oi; }
    }
    const float4* xp = (const float4*)(X + (size_t)row * DIM + lane * 8);
    const float4* wp = (const float4*)(W + (size_t)bi  * DIM + lane * 8);
    float4 x0 = xp[0], x1 = xp[1];
    float4 w0 = wp[0], w1 = wp[1];
    float s = 0.f, d0;
    d0 = x0.x - w0.x; s += d0*d0;  d0 = x0.y - w0.y; s += d0*d0;
    d0 = x0.z - w0.z; s += d0*d0;  d0 = x0.w - w0.w; s += d0*d0;
    d0 = x1.x - w1.x; s += d0*d0;  d0 = x1.y - w1.y; s += d0*d0;
    d0 = x1.z - w1.z; s += d0*d0;  d0 = x1.w - w1.w; s += d0*d0;
    #pragma unroll
    for (int d = 1; d < 64; d <<= 1) s += __shfl_xor(s, d);
    if (lane == 0) psum[wv] = s;
    __syncthreads();
    if (threadIdx.x == 0)
        partial[blockIdx.x] = psum[0] + psum[1] + psum[2] + psum[3];
}

// ---------------- K4: final mean over 8192 partials (double accum) ----------------
__global__ void __launch_bounds__(256)
finalize(const float* __restrict__ partial, float* __restrict__ out) {
    __shared__ double sm[256];
    const float4* p = (const float4*)partial;   // 2048 float4s
    double s = 0.0;
    #pragma unroll
    for (int i = 0; i < 8; ++i) {
        float4 v = p[threadIdx.x + i * 256];
        s += (double)v.x + (double)v.y + (double)v.z + (double)v.w;
    }
    sm[threadIdx.x] = s;
    __syncthreads();
    for (int st = 128; st > 0; st >>= 1) {
        if (threadIdx.x < st) sm[threadIdx.x] += sm[threadIdx.x + st];
        __syncthreads();
    }
    if (threadIdx.x == 0)
        out[0] = (float)(sm[0] / (double)((size_t)N_ROWS * DIM));
}

extern "C" void kernel_launch(void* const* d_in, const int* in_sizes, int n_in,
                              void* d_out, int out_size, void* d_ws, size_t ws_size,
                              hipStream_t stream) {
    const float* X = (const float*)d_in[0];   // [32768][512]
    const float* W = (const float*)d_in[1];   // [1024][512]
    char* ws = (char*)d_ws;
    float*  wnorm   = (float*)ws;                         // 4 KB
    float2* pairs   = (float2*)(ws + 4096);               // 4 MB
    float*  partial = (float*)(ws + 4096 + 4194304);      // 32 KB
    short*  Xb      = (short*)(ws + 8388608);             // 32 MB
    short*  Wb      = (short*)(ws + 8388608 + 33554432);  // 1 MB
    float*  out     = (float*)d_out;

    convertX<<<N_ROWS * DIM / (256 * 8), 256, 0, stream>>>(X, Xb);
    convertW<<<N_CODES / 4, 256, 0, stream>>>(W, Wb, wnorm);
    gemm_argmin<<<2048, 256, 0, stream>>>(Xb, Wb, wnorm, pairs);
    combine_loss<<<N_ROWS / 4, 256, 0, stream>>>(X, W, pairs, partial);
    finalize<<<1, 256, 0, stream>>>(partial, out);
}